// Round 13
// baseline (451.756 us; speedup 1.0000x reference)
//
#include <hip/hip_runtime.h>
#include <hip/hip_bf16.h>
#include <cmath>

// Problem constants
constexpr int Bc = 128, Tc = 128, Ac = 16;
constexpr int Dc = 256, Hc = 512, Qc = 128, QIc = 512, Vc = 64, NTk = 13;
// Masked logits: ref emits -inf; harness needs finite there.
constexpr float NEG_BIG = -1e30f;
// fp8 scaling: weights x16, activations x16 (exact pow2), acc x 1/256.
constexpr float ACT_SCALE = 16.f;
constexpr float ACC_SCALE = 1.f / 256.f;
constexpr float ACC_TO_ACT = 1.f / 16.f;  // ACC_SCALE*ACT_SCALE (epilogue fold)

typedef unsigned int uint;
typedef uint uint2v __attribute__((ext_vector_type(2)));
typedef float f32x4 __attribute__((ext_vector_type(4)));

#define MFMA16F8(a, b, c) __builtin_amdgcn_mfma_f32_16x16x32_fp8_fp8(a, b, c, 0, 0, 0)

__device__ __forceinline__ long long u2ll(uint2v v) {
  union { uint2v u; long long l; } x;
  x.u = v;
  return x.l;
}
__device__ __forceinline__ unsigned short f2bfu(float f) {
  __hip_bfloat16 h = __float2bfloat16(f);
  return *(unsigned short*)&h;
}
__device__ __forceinline__ float bf2f(short s) {
  return __uint_as_float(((unsigned)(unsigned short)s) << 16);
}
__device__ __forceinline__ uint pack4_fp8(float a, float b, float c, float d) {
  uint v = 0;
  v = __builtin_amdgcn_cvt_pk_fp8_f32(a, b, v, 0);
  v = __builtin_amdgcn_cvt_pk_fp8_f32(c, d, v, 1);
  return v;
}

// ---------------------------------------------------------------------------
// Weight transform (r11 layout, unchanged): fp32 [P][K][N] -> fp8 (x16)
// fragments. frag[p][nt][kc][lane]: n = nt*16+(lane&15), k = kc*32+(lane>>4)*8+j.
// ---------------------------------------------------------------------------
__global__ void transform_all(const float* __restrict__ kW1, const float* __restrict__ kW2,
                              const float* __restrict__ kW3, const float* __restrict__ qW,
                              uint2v* __restrict__ kW1f, uint2v* __restrict__ kW2f,
                              uint2v* __restrict__ kW3f, uint2v* __restrict__ qWf) {
  int gid = blockIdx.x * 256 + threadIdx.x;
  const float* W;
  uint2v* dst;
  int NT, KC, N, local;
  if (gid < 65536) {            // kW1: P4 x NT32 x KC8
    W = kW1; dst = kW1f; NT = 32; KC = 8; N = 512; local = gid;
  } else if (gid < 196608) {    // kW2: P4 x NT32 x KC16
    W = kW2; dst = kW2f; NT = 32; KC = 16; N = 512; local = gid - 65536;
  } else if (gid < 229376) {    // kW3: P4 x NT8 x KC16
    W = kW3; dst = kW3f; NT = 8; KC = 16; N = 128; local = gid - 196608;
  } else {                      // qW:  P4 x NT8 x KC16
    W = qW; dst = qWf; NT = 8; KC = 16; N = 128; local = gid - 229376;
  }
  int lane = local & 63;
  int frag = local >> 6;
  int kc = frag % KC;
  int rest = frag / KC;
  int nt = rest % NT;
  int p = rest / NT;
  int K = KC * 32;
  int n = nt * 16 + (lane & 15);
  int k0 = kc * 32 + (lane >> 4) * 8;
  const float* src = W + ((size_t)p * K + k0) * N + n;
  float f[8];
#pragma unroll
  for (int j = 0; j < 8; ++j) f[j] = src[(size_t)j * N] * ACT_SCALE;
  uint2v v;
  v.x = pack4_fp8(f[0], f[1], f[2], f[3]);
  v.y = pack4_fp8(f[4], f[5], f[6], f[7]);
  dst[local] = v;
}

// ---------------------------------------------------------------------------
// fp8 16x16x32 MFMA layer (r13: M=32 blocks -> acc = WT*AT*4 = 16 regs).
// Weights = A (WT outdim-tiles), activations = B (AT action-tiles), K=KC*32.
// Both weight loads issue at the TOP of each kc iteration (r11 serialized
// wt1's load behind wt0's MFMAs), then the LDS reads, then 8 MFMAs — the two
// ~200cyc L2 loads overlap each other and the ds_reads. With acc=16 the
// whole live set is ~52 regs < 64 (8 waves/EU budget): no spill (r7/r8/r12
// all spilled at acc=32 + widened operands; WRITE_SIZE is the guardrail).
// A/B frag: 16-dim = lane&15, k=(lane>>4)*8+j. C/D: lane = action (B-row),
// 4 consecutive outdims (4q+r) -> packed dword/b64/float4 stores.
// OUTMODE: 0 = fp8 x16 (hidden), 1 = bf16 (KV), 2 = fp32 token rows (QY).
// ---------------------------------------------------------------------------
template <int KC, int WT, int AT, bool RELU, int OUTMODE, int SIN, int SOUT>
__device__ __forceinline__ void layer16(
    const char* __restrict__ aB, void* __restrict__ o0,
    const uint2v* __restrict__ Wf, const float* __restrict__ bias,
    int wt0, int lane) {
  const int c = lane & 15, q = lane >> 4;
  const char* ap = aB + c * SIN + q * 8;

  f32x4 acc[WT][AT];
#pragma unroll
  for (int wt = 0; wt < WT; ++wt)
#pragma unroll
    for (int at = 0; at < AT; ++at)
#pragma unroll
      for (int r = 0; r < 4; ++r) acc[wt][at][r] = 0.f;

#pragma unroll 1
  for (int kc = 0; kc < KC; ++kc) {
    // issue all global weight loads first (long latency), then LDS reads
    uint2v wv[WT];
#pragma unroll
    for (int wt = 0; wt < WT; ++wt) {
      const uint2v* wk = Wf + ((size_t)(wt0 + wt) * KC + kc) * 64;
      wv[wt] = wk[lane];  // wave-uniform base + lane -> saddr load, 0 VALU
    }
    uint2v af[AT];
#pragma unroll
    for (int at = 0; at < AT; ++at)
      af[at] = *(const uint2v*)(ap + at * 16 * SIN + kc * 32);
#pragma unroll
    for (int wt = 0; wt < WT; ++wt) {
      long long ww = u2ll(wv[wt]);
#pragma unroll
      for (int at = 0; at < AT; ++at)
        acc[wt][at] = MFMA16F8(ww, u2ll(af[at]), acc[wt][at]);
    }
  }

#pragma unroll
  for (int wt = 0; wt < WT; ++wt) {
    const int nb = (wt0 + wt) * 16 + 4 * q;  // outdim base for this lane
    float4 bv = *(const float4*)(bias + nb);
#pragma unroll
    for (int at = 0; at < AT; ++at) {
      const int row = at * 16 + c;  // action row
      if (OUTMODE == 0) {
        float s0 = fmaf(acc[wt][at][0], ACC_TO_ACT, bv.x * ACT_SCALE);
        float s1 = fmaf(acc[wt][at][1], ACC_TO_ACT, bv.y * ACT_SCALE);
        float s2 = fmaf(acc[wt][at][2], ACC_TO_ACT, bv.z * ACT_SCALE);
        float s3 = fmaf(acc[wt][at][3], ACC_TO_ACT, bv.w * ACT_SCALE);
        if (RELU) {
          s0 = fmaxf(s0, 0.f); s1 = fmaxf(s1, 0.f);
          s2 = fmaxf(s2, 0.f); s3 = fmaxf(s3, 0.f);
        }
        *(uint*)((char*)o0 + row * SOUT + nb) = pack4_fp8(s0, s1, s2, s3);
      } else if (OUTMODE == 1) {
        float s0 = fmaf(acc[wt][at][0], ACC_SCALE, bv.x);
        float s1 = fmaf(acc[wt][at][1], ACC_SCALE, bv.y);
        float s2 = fmaf(acc[wt][at][2], ACC_SCALE, bv.z);
        float s3 = fmaf(acc[wt][at][3], ACC_SCALE, bv.w);
        uint2v u;
        u.x = ((uint)f2bfu(s1) << 16) | f2bfu(s0);
        u.y = ((uint)f2bfu(s3) << 16) | f2bfu(s2);
        *(uint2v*)((short*)o0 + row * SOUT + nb) = u;
      } else {
        if (c < 4) {  // token rows (2 real + 2 scratch rows in QYs[4])
          float4 st;
          st.x = fmaf(acc[wt][at][0], ACC_SCALE, bv.x);
          st.y = fmaf(acc[wt][at][1], ACC_SCALE, bv.y);
          st.z = fmaf(acc[wt][at][2], ACC_SCALE, bv.z);
          st.w = fmaf(acc[wt][at][3], ACC_SCALE, bv.w);
          *(float4*)((float*)o0 + c * SOUT + nb) = st;
        }
      }
    }
  }
}

// ---------------------------------------------------------------------------
// Main fused kernel (r13): 1024 threads (16 waves), M=32 rows
// (2 tokens x 16 actions), 8192 blocks. acc=16 + arch~36 regs -> no spill at
// 8 waves/EU; 2 blocks x 16 waves = 32 waves/CU (max).
// phase = blockIdx&3 -> per-phase 512KB fp8 weight set stays L2-resident
// (2x L2 weight traffic vs r11: ~4GB @ ~16TB/s, well under 34.5TB/s ceiling).
// ---------------------------------------------------------------------------
constexpr int SX = 280;   // Xs row stride bytes
constexpr int SH = 536;   // H1/H2/beA row stride bytes
constexpr int SKV = 136;  // KV stride (bf16 elems)
constexpr int SQY = 132;  // QY stride (fp32 elems)

__global__ __launch_bounds__(1024, 8) void policy_main(
    const float* __restrict__ be, const int* __restrict__ va,
    const int* __restrict__ phase, const int* __restrict__ trick,
    const float* __restrict__ emb0, const float* __restrict__ emb1,
    const float* __restrict__ emb2, const float* __restrict__ ln_g,
    const float* __restrict__ ln_b,
    const float* __restrict__ kb1, const float* __restrict__ kb2,
    const float* __restrict__ kb3, const float* __restrict__ qb,
    const uint2v* __restrict__ kW1f, const uint2v* __restrict__ kW2f,
    const uint2v* __restrict__ kW3f, const uint2v* __restrict__ qWf,
    float* __restrict__ out) {
  __shared__ __align__(16) char bufA[32 * SH];   // Xs [32][SX] then H2 [32][SH]
  __shared__ __align__(16) char bufB[32 * SH];   // H1 [32][SH]; then KV+QY
  __shared__ __align__(16) char beAb[16 * SH];   // be tokens fp8 rows 0..1 (2..15 garbage)
  __shared__ float attn_s[32];
  __shared__ char inval_s[32];
  __shared__ int ph_s[2], tr_s[2];

  char* Xs = bufA;
  char* H2 = bufA;
  char* H1 = bufB;
  short* KV = (short*)bufB;                  // [32][SKV] bf16 (8704B, H1 dead)
  float* QYs = (float*)(bufB + 8704);        // [4][SQY] fp32 (2112B)

  const int tid = threadIdx.x;
  const int w = tid >> 6, lane = tid & 63;
  const int p = blockIdx.x & 3;
  const int g = blockIdx.x >> 2;         // 0..2047
  const int b = g >> 4;                  // 0..127
  const int t0 = p * 32 + (g & 15) * 2;  // 2 tokens per block within phase window
  const int bt0 = b * Tc + t0;

  // ---- stage 0 (no internal barrier): LN->Xs, beA, masks, phase/trick ----
  if (tid < 512) {
    // embed-sum + LayerNorm -> Xs fp8 x16 (16 thr/row x 16 dims), rows 0..31
    const int r = tid >> 4, part = tid & 15, d0 = part * 16;
    const int* vp = va + ((size_t)bt0 * Ac + r) * 3;
    int i0 = min(max(vp[0], 0), Vc - 1);
    int i1 = min(max(vp[1], 0), Vc - 1);
    int i2 = min(max(vp[2], 0), Vc - 1);
    const float4* e0 = (const float4*)(emb0 + i0 * Dc + d0);
    const float4* e1 = (const float4*)(emb1 + i1 * Dc + d0);
    const float4* e2 = (const float4*)(emb2 + i2 * Dc + d0);
    float xv[16];
    float sum = 0.f, ss = 0.f;
#pragma unroll
    for (int j = 0; j < 4; ++j) {
      float4 v0 = e0[j], v1 = e1[j], v2 = e2[j];
      float4 v;
      v.x = v0.x + v1.x + v2.x; v.y = v0.y + v1.y + v2.y;
      v.z = v0.z + v1.z + v2.z; v.w = v0.w + v1.w + v2.w;
      xv[j * 4 + 0] = v.x; xv[j * 4 + 1] = v.y; xv[j * 4 + 2] = v.z; xv[j * 4 + 3] = v.w;
      sum += v.x + v.y + v.z + v.w;
      ss += v.x * v.x + v.y * v.y + v.z * v.z + v.w * v.w;
    }
    sum += __shfl_xor(sum, 1); sum += __shfl_xor(sum, 2);
    sum += __shfl_xor(sum, 4); sum += __shfl_xor(sum, 8);
    ss += __shfl_xor(ss, 1);   ss += __shfl_xor(ss, 2);
    ss += __shfl_xor(ss, 4);   ss += __shfl_xor(ss, 8);
    const float mu = sum / (float)Dc;
    const float rstd = rsqrtf(ss / (float)Dc - mu * mu + 1e-5f);
    float y[16];
#pragma unroll
    for (int j = 0; j < 16; ++j) {
      int d = d0 + j;
      y[j] = ((xv[j] - mu) * rstd * ln_g[d] + ln_b[d]) * ACT_SCALE;
    }
    uint2v v8;
    v8.x = pack4_fp8(y[0], y[1], y[2], y[3]);
    v8.y = pack4_fp8(y[4], y[5], y[6], y[7]);
    *(uint2v*)(Xs + r * SX + d0) = v8;
    v8.x = pack4_fp8(y[8], y[9], y[10], y[11]);
    v8.y = pack4_fp8(y[12], y[13], y[14], y[15]);
    *(uint2v*)(Xs + r * SX + d0 + 8) = v8;
  } else if (tid < 640) {  // beA rows 0..1 (x16 fp8)
    int i = tid - 512;
    int tok = i >> 6, d0 = (i & 63) * 8;
    const float* bp = be + ((size_t)bt0 + tok) * QIc + d0;
    uint2v v8;
    v8.x = pack4_fp8(bp[0] * ACT_SCALE, bp[1] * ACT_SCALE, bp[2] * ACT_SCALE, bp[3] * ACT_SCALE);
    v8.y = pack4_fp8(bp[4] * ACT_SCALE, bp[5] * ACT_SCALE, bp[6] * ACT_SCALE, bp[7] * ACT_SCALE);
    *(uint2v*)(beAb + tok * SH + d0) = v8;
  } else if (tid < 672) {
    int i = tid - 640;
    inval_s[i] = (va[((size_t)bt0 * Ac + i) * 3] == -1);
  } else if (tid < 674) {
    ph_s[tid - 672] = phase[bt0 + tid - 672];
  } else if (tid < 676) {
    tr_s[tid - 674] = trick[bt0 + tid - 674];
  }
  __syncthreads();

  // ---- layer1: X(32x256) @ kW1 -> H1(32x512) relu. 16 waves x 2wt x 2at ----
  layer16<8, 2, 2, true, 0, SX, SH>(Xs, H1, kW1f + (size_t)p * 32 * 8 * 64,
                                    kb1 + p * Hc, w * 2, lane);
  __syncthreads();

  // ---- layer2: H1(32x512) @ kW2 -> H2(32x512) relu ----
  layer16<16, 2, 2, true, 0, SH, SH>(H1, H2, kW2f + (size_t)p * 32 * 16 * 64,
                                     kb2 + p * Hc, w * 2, lane);
  __syncthreads();

  // ---- layer3 (waves 0-7) -> KV bf16; query (waves 8-15) -> QY fp32 ----
  if (w < 8) {
    layer16<16, 1, 2, false, 1, SH, SKV>(H2, KV, kW3f + (size_t)p * 8 * 16 * 64,
                                         kb3 + p * Qc, w, lane);
  } else {
    layer16<16, 1, 1, false, 2, SH, SQY>(beAb, QYs, qWf + (size_t)p * 8 * 16 * 64,
                                         qb + p * Qc, w - 8, lane);
  }
  __syncthreads();

  // ---- attn[r] = <QY[tok], KV[r]> / sqrt(Q) (16 thr/row x 8 dims) ----
  if (tid < 512) {
    const int r = tid >> 4, part = tid & 15, tok = r >> 4;
    const short* kp = KV + r * SKV + part * 8;
    const float* qp = QYs + tok * SQY + part * 8;
    float s = 0.f;
#pragma unroll
    for (int j = 0; j < 8; ++j) s += bf2f(kp[j]) * qp[j];
    s += __shfl_xor(s, 1); s += __shfl_xor(s, 2);
    s += __shfl_xor(s, 4); s += __shfl_xor(s, 8);
    if (part == 0) attn_s[r] = s * 0.08838834764831845f;  // 1/sqrt(128)
  }
  __syncthreads();

  // ---- mask, signal weight, log_softmax, store (one thread per token) ----
  if (tid < 2) {
    const int tok = tid;
    const int bt = bt0 + tok;
    float av[Ac];
    int nv = 0;
#pragma unroll
    for (int a = 0; a < Ac; ++a) {
      int iv = inval_s[tok * Ac + a];
      nv += iv ? 0 : 1;
      av[a] = iv ? NEG_BIG : attn_s[tok * Ac + a];
    }
    if (ph_s[tok] == 1) {
      const int nt = NTk - tr_s[tok];
      float dp = 1.f;
      for (int i = 0; i < nt; ++i) dp *= 0.6f;
      const float ps = 0.4f / (1.f - dp);
      float wgt = (nv == 1) ? 0.f : logf(fmaxf((1.f - ps) / ps * ((float)nv - 1.f), 1e-5f));
      av[0] += wgt;
    }
    float m = NEG_BIG;
#pragma unroll
    for (int a = 0; a < Ac; ++a) m = fmaxf(m, av[a]);
    float s = 0.f;
#pragma unroll
    for (int a = 0; a < Ac; ++a) s += expf(av[a] - m);
    const float lse = logf(s) + m;
#pragma unroll
    for (int a = 0; a < Ac; ++a)
      out[bt * Ac + a] = inval_s[tok * Ac + a] ? NEG_BIG : (av[a] - lse);
  }
}

extern "C" void kernel_launch(void* const* d_in, const int* in_sizes, int n_in,
                              void* d_out, int out_size, void* d_ws, size_t ws_size,
                              hipStream_t stream) {
  const float* be   = (const float*)d_in[0];
  const int*   va   = (const int*)d_in[1];
  const int*   ph   = (const int*)d_in[2];
  const int*   tr   = (const int*)d_in[3];
  const float* emb0 = (const float*)d_in[4];
  const float* emb1 = (const float*)d_in[5];
  const float* emb2 = (const float*)d_in[6];
  const float* lng  = (const float*)d_in[7];
  const float* lnb  = (const float*)d_in[8];
  const float* kW1  = (const float*)d_in[9];
  const float* kb1  = (const float*)d_in[10];
  const float* kW2  = (const float*)d_in[11];
  const float* kb2  = (const float*)d_in[12];
  const float* kW3  = (const float*)d_in[13];
  const float* kb3  = (const float*)d_in[14];
  const float* qW   = (const float*)d_in[15];
  const float* qb   = (const float*)d_in[16];
  float* out = (float*)d_out;

  // d_ws (fp8 fragments): kW1f 512KB | kW2f 1MB | kW3f 256KB | qWf 256KB = 2MB
  uint2v* kW1f = (uint2v*)d_ws;
  uint2v* kW2f = kW1f + 65536;
  uint2v* kW3f = kW2f + 131072;
  uint2v* qWf  = kW3f + 32768;

  transform_all<<<262144 / 256, 256, 0, stream>>>(kW1, kW2, kW3, qW, kW1f, kW2f, kW3f, qWf);

  policy_main<<<8192, 1024, 0, stream>>>(be, va, ph, tr, emb0, emb1, emb2, lng, lnb,
                                         kb1, kb2, kb3, qb, kW1f, kW2f, kW3f, qWf, out);
}

// Round 14
// 430.774 us; speedup vs baseline: 1.0487x; 1.0487x over previous
//
#include <hip/hip_runtime.h>
#include <hip/hip_bf16.h>
#include <cmath>

// Problem constants
constexpr int Bc = 128, Tc = 128, Ac = 16;
constexpr int Dc = 256, Hc = 512, Qc = 128, QIc = 512, Vc = 64, NTk = 13;
// Masked logits: ref emits -inf; harness needs finite there.
constexpr float NEG_BIG = -1e30f;
// fp8 scaling: weights x16, activations x16 (exact pow2), acc x 1/256.
constexpr float ACT_SCALE = 16.f;
constexpr float ACC_SCALE = 1.f / 256.f;
constexpr float ACC_TO_ACT = 1.f / 16.f;  // ACC_SCALE*ACT_SCALE (epilogue fold)

typedef unsigned int uint;
typedef uint uint2v __attribute__((ext_vector_type(2)));
typedef float f32x4 __attribute__((ext_vector_type(4)));

#define MFMA16F8(a, b, c) __builtin_amdgcn_mfma_f32_16x16x32_fp8_fp8(a, b, c, 0, 0, 0)

__device__ __forceinline__ long long u2ll(uint2v v) {
  union { uint2v u; long long l; } x;
  x.u = v;
  return x.l;
}
__device__ __forceinline__ unsigned short f2bfu(float f) {
  __hip_bfloat16 h = __float2bfloat16(f);
  return *(unsigned short*)&h;
}
__device__ __forceinline__ float bf2f(short s) {
  return __uint_as_float(((unsigned)(unsigned short)s) << 16);
}
__device__ __forceinline__ uint pack4_fp8(float a, float b, float c, float d) {
  uint v = 0;
  v = __builtin_amdgcn_cvt_pk_fp8_f32(a, b, v, 0);
  v = __builtin_amdgcn_cvt_pk_fp8_f32(c, d, v, 1);
  return v;
}

// ---------------------------------------------------------------------------
// Weight transform (r11 layout, unchanged): fp32 [P][K][N] -> fp8 (x16)
// fragments. frag[p][nt][kc][lane]: n = nt*16+(lane&15), k = kc*32+(lane>>4)*8+j.
// ---------------------------------------------------------------------------
__global__ void transform_all(const float* __restrict__ kW1, const float* __restrict__ kW2,
                              const float* __restrict__ kW3, const float* __restrict__ qW,
                              uint2v* __restrict__ kW1f, uint2v* __restrict__ kW2f,
                              uint2v* __restrict__ kW3f, uint2v* __restrict__ qWf) {
  int gid = blockIdx.x * 256 + threadIdx.x;
  const float* W;
  uint2v* dst;
  int NT, KC, N, local;
  if (gid < 65536) {            // kW1: P4 x NT32 x KC8
    W = kW1; dst = kW1f; NT = 32; KC = 8; N = 512; local = gid;
  } else if (gid < 196608) {    // kW2: P4 x NT32 x KC16
    W = kW2; dst = kW2f; NT = 32; KC = 16; N = 512; local = gid - 65536;
  } else if (gid < 229376) {    // kW3: P4 x NT8 x KC16
    W = kW3; dst = kW3f; NT = 8; KC = 16; N = 128; local = gid - 196608;
  } else {                      // qW:  P4 x NT8 x KC16
    W = qW; dst = qWf; NT = 8; KC = 16; N = 128; local = gid - 229376;
  }
  int lane = local & 63;
  int frag = local >> 6;
  int kc = frag % KC;
  int rest = frag / KC;
  int nt = rest % NT;
  int p = rest / NT;
  int K = KC * 32;
  int n = nt * 16 + (lane & 15);
  int k0 = kc * 32 + (lane >> 4) * 8;
  const float* src = W + ((size_t)p * K + k0) * N + n;
  float f[8];
#pragma unroll
  for (int j = 0; j < 8; ++j) f[j] = src[(size_t)j * N] * ACT_SCALE;
  uint2v v;
  v.x = pack4_fp8(f[0], f[1], f[2], f[3]);
  v.y = pack4_fp8(f[4], f[5], f[6], f[7]);
  dst[local] = v;
}

// ---------------------------------------------------------------------------
// fp8 16x16x32 MFMA layer, r14: 2x8 wave grid (m-split x n-split).
// Weights = A (WT outdim-tiles from wt0), activations = B (AT action-tiles
// from at0), K = KC*32. r11 had every wave read ALL 64 activation rows
// (AT=4); splitting M across wave groups (AT=2) halves per-block LDS read
// volume — the dominant pipe (~150us/CU in r11). Weight frags are now read
// by 2 waves each (L2 traffic x2, ~16TB/s demand vs 34.5TB/s ceiling: OK).
// Inner loop keeps r11's proven shape: af[AT] LDS loads, then wt-loop with a
// single live wv (acc32 + af4 + wv2 + addr fits the 64-reg 8-wave/EU budget;
// r7/r8/r12 showed widening operands at acc=32 spills -> WRITE_SIZE guard).
// A/B frag: 16-dim = lane&15, k=(lane>>4)*8+j. C/D: lane = action (B-row),
// 4 consecutive outdims (4q+r) -> packed dword/b64/float4 stores.
// OUTMODE: 0 = fp8 x16 (hidden), 1 = bf16 (KV), 2 = fp32 token rows (QY).
// ---------------------------------------------------------------------------
template <int KC, int WT, int AT, bool RELU, int OUTMODE, int SIN, int SOUT>
__device__ __forceinline__ void layer16(
    const char* __restrict__ aB, void* __restrict__ o0,
    const uint2v* __restrict__ Wf, const float* __restrict__ bias,
    int wt0, int at0, int lane) {
  const int c = lane & 15, q = lane >> 4;
  const char* ap = aB + (at0 * 16 + c) * SIN + q * 8;

  f32x4 acc[WT][AT];
#pragma unroll
  for (int wt = 0; wt < WT; ++wt)
#pragma unroll
    for (int at = 0; at < AT; ++at)
#pragma unroll
      for (int r = 0; r < 4; ++r) acc[wt][at][r] = 0.f;

#pragma unroll 1
  for (int kc = 0; kc < KC; ++kc) {
    uint2v af[AT];
#pragma unroll
    for (int at = 0; at < AT; ++at)
      af[at] = *(const uint2v*)(ap + at * 16 * SIN + kc * 32);
#pragma unroll
    for (int wt = 0; wt < WT; ++wt) {
      // wave-uniform base + lane index -> saddr global load (no VALU addr math)
      const uint2v* wk = Wf + ((size_t)(wt0 + wt) * KC + kc) * 64;
      uint2v wv = wk[lane];
      long long ww = u2ll(wv);
#pragma unroll
      for (int at = 0; at < AT; ++at)
        acc[wt][at] = MFMA16F8(ww, u2ll(af[at]), acc[wt][at]);
    }
  }

#pragma unroll
  for (int wt = 0; wt < WT; ++wt) {
    const int nb = (wt0 + wt) * 16 + 4 * q;  // outdim base for this lane
    float4 bv = *(const float4*)(bias + nb);
#pragma unroll
    for (int at = 0; at < AT; ++at) {
      const int row = (at0 + at) * 16 + c;  // action row
      if (OUTMODE == 0) {
        float s0 = fmaf(acc[wt][at][0], ACC_TO_ACT, bv.x * ACT_SCALE);
        float s1 = fmaf(acc[wt][at][1], ACC_TO_ACT, bv.y * ACT_SCALE);
        float s2 = fmaf(acc[wt][at][2], ACC_TO_ACT, bv.z * ACT_SCALE);
        float s3 = fmaf(acc[wt][at][3], ACC_TO_ACT, bv.w * ACT_SCALE);
        if (RELU) {
          s0 = fmaxf(s0, 0.f); s1 = fmaxf(s1, 0.f);
          s2 = fmaxf(s2, 0.f); s3 = fmaxf(s3, 0.f);
        }
        *(uint*)((char*)o0 + row * SOUT + nb) = pack4_fp8(s0, s1, s2, s3);
      } else if (OUTMODE == 1) {
        float s0 = fmaf(acc[wt][at][0], ACC_SCALE, bv.x);
        float s1 = fmaf(acc[wt][at][1], ACC_SCALE, bv.y);
        float s2 = fmaf(acc[wt][at][2], ACC_SCALE, bv.z);
        float s3 = fmaf(acc[wt][at][3], ACC_SCALE, bv.w);
        uint2v u;
        u.x = ((uint)f2bfu(s1) << 16) | f2bfu(s0);
        u.y = ((uint)f2bfu(s3) << 16) | f2bfu(s2);
        *(uint2v*)((short*)o0 + row * SOUT + nb) = u;
      } else {
        if (c < 4) {  // only real token rows
          float4 st;
          st.x = fmaf(acc[wt][at][0], ACC_SCALE, bv.x);
          st.y = fmaf(acc[wt][at][1], ACC_SCALE, bv.y);
          st.z = fmaf(acc[wt][at][2], ACC_SCALE, bv.z);
          st.w = fmaf(acc[wt][at][3], ACC_SCALE, bv.w);
          *(float4*)((float*)o0 + c * SOUT + nb) = st;
        }
      }
    }
  }
}

// ---------------------------------------------------------------------------
// Main fused kernel: 1024 threads (16 waves), 64 rows (4 tokens x 16 actions).
// 32arch+32acc regs -> 2 blocks x 16 waves = 32 waves/CU.
// phase = blockIdx&3 -> per-phase 512KB fp8 weight set stays L2-resident.
// Wave grid for MLP layers: (w>>3) = m-group (rows 0-31 / 32-63),
// (w&7) = n-group (4 consecutive nt each).
// ---------------------------------------------------------------------------
constexpr int SX = 280;   // Xs row stride bytes
constexpr int SH = 536;   // H1/H2/beA row stride bytes
constexpr int SKV = 136;  // KV stride (bf16 elems)
constexpr int SQY = 132;  // QY stride (fp32 elems)

__global__ __launch_bounds__(1024, 8) void policy_main(
    const float* __restrict__ be, const int* __restrict__ va,
    const int* __restrict__ phase, const int* __restrict__ trick,
    const float* __restrict__ emb0, const float* __restrict__ emb1,
    const float* __restrict__ emb2, const float* __restrict__ ln_g,
    const float* __restrict__ ln_b,
    const float* __restrict__ kb1, const float* __restrict__ kb2,
    const float* __restrict__ kb3, const float* __restrict__ qb,
    const uint2v* __restrict__ kW1f, const uint2v* __restrict__ kW2f,
    const uint2v* __restrict__ kW3f, const uint2v* __restrict__ qWf,
    float* __restrict__ out) {
  __shared__ __align__(16) char bufA[64 * SH];   // Xs [64][SX] then H2 [64][SH]
  __shared__ __align__(16) char bufB[64 * SH];   // H1 [64][SH]; then KV+QY
  __shared__ __align__(16) char beAb[16 * SH];   // be tokens fp8 (rows 4..15 garbage)
  __shared__ float attn_s[64];
  __shared__ char inval_s[64];
  __shared__ int ph_s[4], tr_s[4];

  char* Xs = bufA;
  char* H2 = bufA;
  char* H1 = bufB;
  short* KV = (short*)bufB;                  // [64][SKV] bf16 (17408B, H1 dead)
  float* QYs = (float*)(bufB + 17408);       // [4][SQY] fp32 (2112B)

  const int tid = threadIdx.x;
  const int w = tid >> 6, lane = tid & 63;
  const int p = blockIdx.x & 3;
  const int g = blockIdx.x >> 2;
  const int b = g >> 3;
  const int t0 = p * 32 + (g & 7) * 4;
  const int bt0 = b * Tc + t0;

  // ---- stage 0 (no internal barrier): masks, phase/trick, beA, LN->Xs ----
  if (tid < 64) {
    inval_s[tid] = (va[((size_t)bt0 * Ac + tid) * 3] == -1);
  } else if (tid < 68) {
    ph_s[tid - 64] = phase[bt0 + tid - 64];
  } else if (tid < 72) {
    tr_s[tid - 68] = trick[bt0 + tid - 68];
  }
  if (tid < 256) {  // beA rows 0..3 (x16 fp8)
    int tok = tid >> 6, d0 = (tid & 63) * 8;
    const float* bp = be + ((size_t)bt0 + tok) * QIc + d0;
    uint2v v8;
    v8.x = pack4_fp8(bp[0] * ACT_SCALE, bp[1] * ACT_SCALE, bp[2] * ACT_SCALE, bp[3] * ACT_SCALE);
    v8.y = pack4_fp8(bp[4] * ACT_SCALE, bp[5] * ACT_SCALE, bp[6] * ACT_SCALE, bp[7] * ACT_SCALE);
    *(uint2v*)(beAb + tok * SH + d0) = v8;
  }
  {
    // embed-sum + LayerNorm -> Xs fp8 x16 (16 thr/row x 16 dims)
    const int r = tid >> 4, part = tid & 15, d0 = part * 16;
    const int* vp = va + ((size_t)bt0 * Ac + r) * 3;
    int i0 = min(max(vp[0], 0), Vc - 1);
    int i1 = min(max(vp[1], 0), Vc - 1);
    int i2 = min(max(vp[2], 0), Vc - 1);
    const float4* e0 = (const float4*)(emb0 + i0 * Dc + d0);
    const float4* e1 = (const float4*)(emb1 + i1 * Dc + d0);
    const float4* e2 = (const float4*)(emb2 + i2 * Dc + d0);
    float xv[16];
    float sum = 0.f, ss = 0.f;
#pragma unroll
    for (int j = 0; j < 4; ++j) {
      float4 v0 = e0[j], v1 = e1[j], v2 = e2[j];
      float4 v;
      v.x = v0.x + v1.x + v2.x; v.y = v0.y + v1.y + v2.y;
      v.z = v0.z + v1.z + v2.z; v.w = v0.w + v1.w + v2.w;
      xv[j * 4 + 0] = v.x; xv[j * 4 + 1] = v.y; xv[j * 4 + 2] = v.z; xv[j * 4 + 3] = v.w;
      sum += v.x + v.y + v.z + v.w;
      ss += v.x * v.x + v.y * v.y + v.z * v.z + v.w * v.w;
    }
    sum += __shfl_xor(sum, 1); sum += __shfl_xor(sum, 2);
    sum += __shfl_xor(sum, 4); sum += __shfl_xor(sum, 8);
    ss += __shfl_xor(ss, 1);   ss += __shfl_xor(ss, 2);
    ss += __shfl_xor(ss, 4);   ss += __shfl_xor(ss, 8);
    const float mu = sum / (float)Dc;
    const float rstd = rsqrtf(ss / (float)Dc - mu * mu + 1e-5f);
    float y[16];
#pragma unroll
    for (int j = 0; j < 16; ++j) {
      int d = d0 + j;
      y[j] = ((xv[j] - mu) * rstd * ln_g[d] + ln_b[d]) * ACT_SCALE;
    }
    uint2v v8;
    v8.x = pack4_fp8(y[0], y[1], y[2], y[3]);
    v8.y = pack4_fp8(y[4], y[5], y[6], y[7]);
    *(uint2v*)(Xs + r * SX + d0) = v8;
    v8.x = pack4_fp8(y[8], y[9], y[10], y[11]);
    v8.y = pack4_fp8(y[12], y[13], y[14], y[15]);
    *(uint2v*)(Xs + r * SX + d0 + 8) = v8;
  }
  __syncthreads();

  // ---- layer1: X(64x256) @ kW1 -> H1(64x512) relu. 8n x 2m waves, 4wt x 2at ----
  layer16<8, 4, 2, true, 0, SX, SH>(Xs, H1, kW1f + (size_t)p * 32 * 8 * 64,
                                    kb1 + p * Hc, (w & 7) * 4, (w >> 3) * 2, lane);
  __syncthreads();

  // ---- layer2: H1(64x512) @ kW2 -> H2(64x512) relu ----
  layer16<16, 4, 2, true, 0, SH, SH>(H1, H2, kW2f + (size_t)p * 32 * 16 * 64,
                                     kb2 + p * Hc, (w & 7) * 4, (w >> 3) * 2, lane);
  __syncthreads();

  // ---- layer3 (waves 0-7, 4n x 2m) -> KV bf16; query (waves 8-15) -> QY ----
  if (w < 8) {
    layer16<16, 2, 2, false, 1, SH, SKV>(H2, KV, kW3f + (size_t)p * 8 * 16 * 64,
                                         kb3 + p * Qc, (w & 3) * 2, (w >> 2) * 2, lane);
  } else {
    layer16<16, 1, 1, false, 2, SH, SQY>(beAb, QYs, qWf + (size_t)p * 8 * 16 * 64,
                                         qb + p * Qc, w - 8, 0, lane);
  }
  __syncthreads();

  // ---- attn[r] = <QY[tok], KV[r]> / sqrt(Q) (16 thr/row x 8 dims) ----
  if (tid < 1024) {
    const int r = tid >> 4, part = tid & 15, tok = r >> 4;
    const short* kp = KV + r * SKV + part * 8;
    const float* qp = QYs + tok * SQY + part * 8;
    float s = 0.f;
#pragma unroll
    for (int j = 0; j < 8; ++j) s += bf2f(kp[j]) * qp[j];
    s += __shfl_xor(s, 1); s += __shfl_xor(s, 2);
    s += __shfl_xor(s, 4); s += __shfl_xor(s, 8);
    if (part == 0) attn_s[r] = s * 0.08838834764831845f;  // 1/sqrt(128)
  }
  __syncthreads();

  // ---- mask, signal weight, log_softmax, store (one thread per token) ----
  if (tid < 4) {
    const int tok = tid;
    const int bt = bt0 + tok;
    float av[Ac];
    int nv = 0;
#pragma unroll
    for (int a = 0; a < Ac; ++a) {
      int iv = inval_s[tok * Ac + a];
      nv += iv ? 0 : 1;
      av[a] = iv ? NEG_BIG : attn_s[tok * Ac + a];
    }
    if (ph_s[tok] == 1) {
      const int nt = NTk - tr_s[tok];
      float dp = 1.f;
      for (int i = 0; i < nt; ++i) dp *= 0.6f;
      const float ps = 0.4f / (1.f - dp);
      float wgt = (nv == 1) ? 0.f : logf(fmaxf((1.f - ps) / ps * ((float)nv - 1.f), 1e-5f));
      av[0] += wgt;
    }
    float m = NEG_BIG;
#pragma unroll
    for (int a = 0; a < Ac; ++a) m = fmaxf(m, av[a]);
    float s = 0.f;
#pragma unroll
    for (int a = 0; a < Ac; ++a) s += expf(av[a] - m);
    const float lse = logf(s) + m;
#pragma unroll
    for (int a = 0; a < Ac; ++a)
      out[bt * Ac + a] = inval_s[tok * Ac + a] ? NEG_BIG : (av[a] - lse);
  }
}

extern "C" void kernel_launch(void* const* d_in, const int* in_sizes, int n_in,
                              void* d_out, int out_size, void* d_ws, size_t ws_size,
                              hipStream_t stream) {
  const float* be   = (const float*)d_in[0];
  const int*   va   = (const int*)d_in[1];
  const int*   ph   = (const int*)d_in[2];
  const int*   tr   = (const int*)d_in[3];
  const float* emb0 = (const float*)d_in[4];
  const float* emb1 = (const float*)d_in[5];
  const float* emb2 = (const float*)d_in[6];
  const float* lng  = (const float*)d_in[7];
  const float* lnb  = (const float*)d_in[8];
  const float* kW1  = (const float*)d_in[9];
  const float* kb1  = (const float*)d_in[10];
  const float* kW2  = (const float*)d_in[11];
  const float* kb2  = (const float*)d_in[12];
  const float* kW3  = (const float*)d_in[13];
  const float* kb3  = (const float*)d_in[14];
  const float* qW   = (const float*)d_in[15];
  const float* qb   = (const float*)d_in[16];
  float* out = (float*)d_out;

  // d_ws (fp8 fragments): kW1f 512KB | kW2f 1MB | kW3f 256KB | qWf 256KB = 2MB
  uint2v* kW1f = (uint2v*)d_ws;
  uint2v* kW2f = kW1f + 65536;
  uint2v* kW3f = kW2f + 131072;
  uint2v* qWf  = kW3f + 32768;

  transform_all<<<262144 / 256, 256, 0, stream>>>(kW1, kW2, kW3, qW, kW1f, kW2f, kW3f, qWf);

  policy_main<<<4096, 1024, 0, stream>>>(be, va, ph, tr, emb0, emb1, emb2, lng, lnb,
                                         kb1, kb2, kb3, qb, kW1f, kW2f, kW3f, qWf, out);
}

// Round 15
// 384.937 us; speedup vs baseline: 1.1736x; 1.1191x over previous
//
#include <hip/hip_runtime.h>
#include <hip/hip_bf16.h>
#include <cmath>

// Problem constants
constexpr int Bc = 128, Tc = 128, Ac = 16;
constexpr int Dc = 256, Hc = 512, Qc = 128, QIc = 512, Vc = 64, NTk = 13;
// Masked logits: ref emits -inf; harness needs finite there.
constexpr float NEG_BIG = -1e30f;
// fp8 scaling: weights x16, activations x16 (exact pow2), acc x 1/256.
constexpr float ACT_SCALE = 16.f;
constexpr float ACC_SCALE = 1.f / 256.f;
constexpr float ACC_TO_ACT = 1.f / 16.f;  // ACC_SCALE*ACT_SCALE (epilogue fold)

typedef unsigned int uint;
typedef uint uint2v __attribute__((ext_vector_type(2)));
typedef float f32x4 __attribute__((ext_vector_type(4)));

#define MFMA16F8(a, b, c) __builtin_amdgcn_mfma_f32_16x16x32_fp8_fp8(a, b, c, 0, 0, 0)

__device__ __forceinline__ long long u2ll(uint2v v) {
  union { uint2v u; long long l; } x;
  x.u = v;
  return x.l;
}
__device__ __forceinline__ unsigned short f2bfu(float f) {
  __hip_bfloat16 h = __float2bfloat16(f);
  return *(unsigned short*)&h;
}
__device__ __forceinline__ float bf2f(short s) {
  return __uint_as_float(((unsigned)(unsigned short)s) << 16);
}
__device__ __forceinline__ uint pack4_fp8(float a, float b, float c, float d) {
  uint v = 0;
  v = __builtin_amdgcn_cvt_pk_fp8_f32(a, b, v, 0);
  v = __builtin_amdgcn_cvt_pk_fp8_f32(c, d, v, 1);
  return v;
}

// ---------------------------------------------------------------------------
// Weight transform (r11 layout, unchanged): fp32 [P][K][N] -> fp8 (x16)
// fragments. frag[p][nt][kc][lane]: n = nt*16+(lane&15), k = kc*32+(lane>>4)*8+j.
// ---------------------------------------------------------------------------
__global__ void transform_all(const float* __restrict__ kW1, const float* __restrict__ kW2,
                              const float* __restrict__ kW3, const float* __restrict__ qW,
                              uint2v* __restrict__ kW1f, uint2v* __restrict__ kW2f,
                              uint2v* __restrict__ kW3f, uint2v* __restrict__ qWf) {
  int gid = blockIdx.x * 256 + threadIdx.x;
  const float* W;
  uint2v* dst;
  int NT, KC, N, local;
  if (gid < 65536) {            // kW1: P4 x NT32 x KC8
    W = kW1; dst = kW1f; NT = 32; KC = 8; N = 512; local = gid;
  } else if (gid < 196608) {    // kW2: P4 x NT32 x KC16
    W = kW2; dst = kW2f; NT = 32; KC = 16; N = 512; local = gid - 65536;
  } else if (gid < 229376) {    // kW3: P4 x NT8 x KC16
    W = kW3; dst = kW3f; NT = 8; KC = 16; N = 128; local = gid - 196608;
  } else {                      // qW:  P4 x NT8 x KC16
    W = qW; dst = qWf; NT = 8; KC = 16; N = 128; local = gid - 229376;
  }
  int lane = local & 63;
  int frag = local >> 6;
  int kc = frag % KC;
  int rest = frag / KC;
  int nt = rest % NT;
  int p = rest / NT;
  int K = KC * 32;
  int n = nt * 16 + (lane & 15);
  int k0 = kc * 32 + (lane >> 4) * 8;
  const float* src = W + ((size_t)p * K + k0) * N + n;
  float f[8];
#pragma unroll
  for (int j = 0; j < 8; ++j) f[j] = src[(size_t)j * N] * ACT_SCALE;
  uint2v v;
  v.x = pack4_fp8(f[0], f[1], f[2], f[3]);
  v.y = pack4_fp8(f[4], f[5], f[6], f[7]);
  dst[local] = v;
}

// ---------------------------------------------------------------------------
// fp8 16x16x32 MFMA layer, r15: r11 tiling + manual 2-deep weight prefetch.
// Weights = A (WT outdim-tiles), activations = B (AT action-tiles), K=KC*32.
// r13/r14 established the binding cost is the L2 weight-load latency in
// front of each MFMA group (1 load per 4 MFMAs is the minimum ratio, r11).
// Here the kc loop steps by 2 with explicit wvA/wvB alternation: iteration
// kc's MFMAs run while kc+1's weight loads are in flight (~37cyc MFMA + af
// issue vs ~200cyc L2 latency, x8 waves TLP). ONLY the weight loads are
// pipelined — af stays in-iteration (r8's compiler unroll-2 pipelined
// everything and spilled 128MB; live set here: acc32+wvA4+wvB4+af8+addr~58).
// WRITE_SIZE is the spill guardrail.
// A/B frag: 16-dim = lane&15, k=(lane>>4)*8+j. C/D: lane = action (B-row),
// 4 consecutive outdims (4q+r) -> packed dword/b64/float4 stores.
// OUTMODE: 0 = fp8 x16 (hidden), 1 = bf16 (KV), 2 = fp32 token rows (QY).
// ---------------------------------------------------------------------------
template <int KC, int WT, int AT, bool RELU, int OUTMODE, int SIN, int SOUT>
__device__ __forceinline__ void layer16(
    const char* __restrict__ aB, void* __restrict__ o0,
    const uint2v* __restrict__ Wf, const float* __restrict__ bias,
    int wt0, int lane) {
  const int c = lane & 15, q = lane >> 4;
  const char* ap = aB + c * SIN + q * 8;
  const uint2v* wl = Wf + (size_t)wt0 * KC * 64 + lane;  // lane-resolved base

  f32x4 acc[WT][AT];
#pragma unroll
  for (int wt = 0; wt < WT; ++wt)
#pragma unroll
    for (int at = 0; at < AT; ++at)
#pragma unroll
      for (int r = 0; r < 4; ++r) acc[wt][at][r] = 0.f;

  uint2v wvA[WT], wvB[WT];
#pragma unroll
  for (int wt = 0; wt < WT; ++wt) wvA[wt] = wl[(wt * KC + 0) * 64];  // kc=0

#pragma unroll 1
  for (int kc = 0; kc < KC; kc += 2) {
    // ---- half A: consume wvA (kc), prefetch wvB (kc+1) ----
    {
      uint2v af[AT];
#pragma unroll
      for (int at = 0; at < AT; ++at)
        af[at] = *(const uint2v*)(ap + at * 16 * SIN + kc * 32);
#pragma unroll
      for (int wt = 0; wt < WT; ++wt) wvB[wt] = wl[(wt * KC + kc + 1) * 64];
#pragma unroll
      for (int wt = 0; wt < WT; ++wt) {
        long long ww = u2ll(wvA[wt]);
#pragma unroll
        for (int at = 0; at < AT; ++at)
          acc[wt][at] = MFMA16F8(ww, u2ll(af[at]), acc[wt][at]);
      }
    }
    // ---- half B: consume wvB (kc+1), prefetch wvA (kc+2, clamped) ----
    {
      const int kcn = (kc + 2 < KC) ? kc + 2 : 0;  // last pair: redundant reload
      uint2v af[AT];
#pragma unroll
      for (int at = 0; at < AT; ++at)
        af[at] = *(const uint2v*)(ap + at * 16 * SIN + (kc + 1) * 32);
#pragma unroll
      for (int wt = 0; wt < WT; ++wt) wvA[wt] = wl[(wt * KC + kcn) * 64];
#pragma unroll
      for (int wt = 0; wt < WT; ++wt) {
        long long ww = u2ll(wvB[wt]);
#pragma unroll
        for (int at = 0; at < AT; ++at)
          acc[wt][at] = MFMA16F8(ww, u2ll(af[at]), acc[wt][at]);
      }
    }
  }

#pragma unroll
  for (int wt = 0; wt < WT; ++wt) {
    const int nb = (wt0 + wt) * 16 + 4 * q;  // outdim base for this lane
    float4 bv = *(const float4*)(bias + nb);
#pragma unroll
    for (int at = 0; at < AT; ++at) {
      const int row = at * 16 + c;  // action row
      if (OUTMODE == 0) {
        float s0 = fmaf(acc[wt][at][0], ACC_TO_ACT, bv.x * ACT_SCALE);
        float s1 = fmaf(acc[wt][at][1], ACC_TO_ACT, bv.y * ACT_SCALE);
        float s2 = fmaf(acc[wt][at][2], ACC_TO_ACT, bv.z * ACT_SCALE);
        float s3 = fmaf(acc[wt][at][3], ACC_TO_ACT, bv.w * ACT_SCALE);
        if (RELU) {
          s0 = fmaxf(s0, 0.f); s1 = fmaxf(s1, 0.f);
          s2 = fmaxf(s2, 0.f); s3 = fmaxf(s3, 0.f);
        }
        *(uint*)((char*)o0 + row * SOUT + nb) = pack4_fp8(s0, s1, s2, s3);
      } else if (OUTMODE == 1) {
        float s0 = fmaf(acc[wt][at][0], ACC_SCALE, bv.x);
        float s1 = fmaf(acc[wt][at][1], ACC_SCALE, bv.y);
        float s2 = fmaf(acc[wt][at][2], ACC_SCALE, bv.z);
        float s3 = fmaf(acc[wt][at][3], ACC_SCALE, bv.w);
        uint2v u;
        u.x = ((uint)f2bfu(s1) << 16) | f2bfu(s0);
        u.y = ((uint)f2bfu(s3) << 16) | f2bfu(s2);
        *(uint2v*)((short*)o0 + row * SOUT + nb) = u;
      } else {
        if (c < 4) {  // only real token rows
          float4 st;
          st.x = fmaf(acc[wt][at][0], ACC_SCALE, bv.x);
          st.y = fmaf(acc[wt][at][1], ACC_SCALE, bv.y);
          st.z = fmaf(acc[wt][at][2], ACC_SCALE, bv.z);
          st.w = fmaf(acc[wt][at][3], ACC_SCALE, bv.w);
          *(float4*)((float*)o0 + c * SOUT + nb) = st;
        }
      }
    }
  }
}

// ---------------------------------------------------------------------------
// Main fused kernel (r11 structure): 1024 threads (16 waves), 64 rows
// (4 tokens x 16 actions). 32arch+32acc regs -> 2 blocks x 16 waves = 32
// waves/CU. phase = blockIdx&3 -> with 8-XCD round-robin dispatch each XCD
// sees exactly one phase: 512KB fp8 weight set L2-resident per XCD.
// ---------------------------------------------------------------------------
constexpr int SX = 280;   // Xs row stride bytes
constexpr int SH = 536;   // H1/H2/beA row stride bytes
constexpr int SKV = 136;  // KV stride (bf16 elems)
constexpr int SQY = 132;  // QY stride (fp32 elems)

__global__ __launch_bounds__(1024, 8) void policy_main(
    const float* __restrict__ be, const int* __restrict__ va,
    const int* __restrict__ phase, const int* __restrict__ trick,
    const float* __restrict__ emb0, const float* __restrict__ emb1,
    const float* __restrict__ emb2, const float* __restrict__ ln_g,
    const float* __restrict__ ln_b,
    const float* __restrict__ kb1, const float* __restrict__ kb2,
    const float* __restrict__ kb3, const float* __restrict__ qb,
    const uint2v* __restrict__ kW1f, const uint2v* __restrict__ kW2f,
    const uint2v* __restrict__ kW3f, const uint2v* __restrict__ qWf,
    float* __restrict__ out) {
  __shared__ __align__(16) char bufA[64 * SH];   // Xs [64][SX] then H2 [64][SH]
  __shared__ __align__(16) char bufB[64 * SH];   // H1 [64][SH]; then KV+QY
  __shared__ __align__(16) char beAb[16 * SH];   // be tokens fp8 (rows 4..15 garbage)
  __shared__ float attn_s[64];
  __shared__ char inval_s[64];
  __shared__ int ph_s[4], tr_s[4];

  char* Xs = bufA;
  char* H2 = bufA;
  char* H1 = bufB;
  short* KV = (short*)bufB;                  // [64][SKV] bf16 (17408B, H1 dead)
  float* QYs = (float*)(bufB + 17408);       // [4][SQY] fp32 (2112B)

  const int tid = threadIdx.x;
  const int w = tid >> 6, lane = tid & 63;
  const int p = blockIdx.x & 3;
  const int g = blockIdx.x >> 2;
  const int b = g >> 3;
  const int t0 = p * 32 + (g & 7) * 4;
  const int bt0 = b * Tc + t0;

  // ---- stage 0 (no internal barrier): masks, phase/trick, beA, LN->Xs ----
  if (tid < 64) {
    inval_s[tid] = (va[((size_t)bt0 * Ac + tid) * 3] == -1);
  } else if (tid < 68) {
    ph_s[tid - 64] = phase[bt0 + tid - 64];
  } else if (tid < 72) {
    tr_s[tid - 68] = trick[bt0 + tid - 68];
  }
  if (tid < 256) {  // beA rows 0..3 (x16 fp8)
    int tok = tid >> 6, d0 = (tid & 63) * 8;
    const float* bp = be + ((size_t)bt0 + tok) * QIc + d0;
    uint2v v8;
    v8.x = pack4_fp8(bp[0] * ACT_SCALE, bp[1] * ACT_SCALE, bp[2] * ACT_SCALE, bp[3] * ACT_SCALE);
    v8.y = pack4_fp8(bp[4] * ACT_SCALE, bp[5] * ACT_SCALE, bp[6] * ACT_SCALE, bp[7] * ACT_SCALE);
    *(uint2v*)(beAb + tok * SH + d0) = v8;
  }
  {
    // embed-sum + LayerNorm -> Xs fp8 x16 (16 thr/row x 16 dims)
    const int r = tid >> 4, part = tid & 15, d0 = part * 16;
    const int* vp = va + ((size_t)bt0 * Ac + r) * 3;
    int i0 = min(max(vp[0], 0), Vc - 1);
    int i1 = min(max(vp[1], 0), Vc - 1);
    int i2 = min(max(vp[2], 0), Vc - 1);
    const float4* e0 = (const float4*)(emb0 + i0 * Dc + d0);
    const float4* e1 = (const float4*)(emb1 + i1 * Dc + d0);
    const float4* e2 = (const float4*)(emb2 + i2 * Dc + d0);
    float xv[16];
    float sum = 0.f, ss = 0.f;
#pragma unroll
    for (int j = 0; j < 4; ++j) {
      float4 v0 = e0[j], v1 = e1[j], v2 = e2[j];
      float4 v;
      v.x = v0.x + v1.x + v2.x; v.y = v0.y + v1.y + v2.y;
      v.z = v0.z + v1.z + v2.z; v.w = v0.w + v1.w + v2.w;
      xv[j * 4 + 0] = v.x; xv[j * 4 + 1] = v.y; xv[j * 4 + 2] = v.z; xv[j * 4 + 3] = v.w;
      sum += v.x + v.y + v.z + v.w;
      ss += v.x * v.x + v.y * v.y + v.z * v.z + v.w * v.w;
    }
    sum += __shfl_xor(sum, 1); sum += __shfl_xor(sum, 2);
    sum += __shfl_xor(sum, 4); sum += __shfl_xor(sum, 8);
    ss += __shfl_xor(ss, 1);   ss += __shfl_xor(ss, 2);
    ss += __shfl_xor(ss, 4);   ss += __shfl_xor(ss, 8);
    const float mu = sum / (float)Dc;
    const float rstd = rsqrtf(ss / (float)Dc - mu * mu + 1e-5f);
    float y[16];
#pragma unroll
    for (int j = 0; j < 16; ++j) {
      int d = d0 + j;
      y[j] = ((xv[j] - mu) * rstd * ln_g[d] + ln_b[d]) * ACT_SCALE;
    }
    uint2v v8;
    v8.x = pack4_fp8(y[0], y[1], y[2], y[3]);
    v8.y = pack4_fp8(y[4], y[5], y[6], y[7]);
    *(uint2v*)(Xs + r * SX + d0) = v8;
    v8.x = pack4_fp8(y[8], y[9], y[10], y[11]);
    v8.y = pack4_fp8(y[12], y[13], y[14], y[15]);
    *(uint2v*)(Xs + r * SX + d0 + 8) = v8;
  }
  __syncthreads();

  // ---- layer1: X(64x256) @ kW1 -> H1(64x512) relu. 16 waves x 2wt x 4at ----
  layer16<8, 2, 4, true, 0, SX, SH>(Xs, H1, kW1f + (size_t)p * 32 * 8 * 64,
                                    kb1 + p * Hc, w * 2, lane);
  __syncthreads();

  // ---- layer2: H1(64x512) @ kW2 -> H2(64x512) relu ----
  layer16<16, 2, 4, true, 0, SH, SH>(H1, H2, kW2f + (size_t)p * 32 * 16 * 64,
                                     kb2 + p * Hc, w * 2, lane);
  __syncthreads();

  // ---- layer3 (waves 0-7) -> KV bf16; query (waves 8-15) -> QY fp32 ----
  if (w < 8) {
    layer16<16, 1, 4, false, 1, SH, SKV>(H2, KV, kW3f + (size_t)p * 8 * 16 * 64,
                                         kb3 + p * Qc, w, lane);
  } else {
    layer16<16, 1, 1, false, 2, SH, SQY>(beAb, QYs, qWf + (size_t)p * 8 * 16 * 64,
                                         qb + p * Qc, w - 8, lane);
  }
  __syncthreads();

  // ---- attn[r] = <QY[tok], KV[r]> / sqrt(Q) (16 thr/row x 8 dims) ----
  {
    const int r = tid >> 4, part = tid & 15, tok = r >> 4;
    const short* kp = KV + r * SKV + part * 8;
    const float* qp = QYs + tok * SQY + part * 8;
    float s = 0.f;
#pragma unroll
    for (int j = 0; j < 8; ++j) s += bf2f(kp[j]) * qp[j];
    s += __shfl_xor(s, 1); s += __shfl_xor(s, 2);
    s += __shfl_xor(s, 4); s += __shfl_xor(s, 8);
    if (part == 0) attn_s[r] = s * 0.08838834764831845f;  // 1/sqrt(128)
  }
  __syncthreads();

  // ---- mask, signal weight, log_softmax, store (one thread per token) ----
  if (tid < 4) {
    const int tok = tid;
    const int bt = bt0 + tok;
    float av[Ac];
    int nv = 0;
#pragma unroll
    for (int a = 0; a < Ac; ++a) {
      int iv = inval_s[tok * Ac + a];
      nv += iv ? 0 : 1;
      av[a] = iv ? NEG_BIG : attn_s[tok * Ac + a];
    }
    if (ph_s[tok] == 1) {
      const int nt = NTk - tr_s[tok];
      float dp = 1.f;
      for (int i = 0; i < nt; ++i) dp *= 0.6f;
      const float ps = 0.4f / (1.f - dp);
      float wgt = (nv == 1) ? 0.f : logf(fmaxf((1.f - ps) / ps * ((float)nv - 1.f), 1e-5f));
      av[0] += wgt;
    }
    float m = NEG_BIG;
#pragma unroll
    for (int a = 0; a < Ac; ++a) m = fmaxf(m, av[a]);
    float s = 0.f;
#pragma unroll
    for (int a = 0; a < Ac; ++a) s += expf(av[a] - m);
    const float lse = logf(s) + m;
#pragma unroll
    for (int a = 0; a < Ac; ++a)
      out[bt * Ac + a] = inval_s[tok * Ac + a] ? NEG_BIG : (av[a] - lse);
  }
}

extern "C" void kernel_launch(void* const* d_in, const int* in_sizes, int n_in,
                              void* d_out, int out_size, void* d_ws, size_t ws_size,
                              hipStream_t stream) {
  const float* be   = (const float*)d_in[0];
  const int*   va   = (const int*)d_in[1];
  const int*   ph   = (const int*)d_in[2];
  const int*   tr   = (const int*)d_in[3];
  const float* emb0 = (const float*)d_in[4];
  const float* emb1 = (const float*)d_in[5];
  const float* emb2 = (const float*)d_in[6];
  const float* lng  = (const float*)d_in[7];
  const float* lnb  = (const float*)d_in[8];
  const float* kW1  = (const float*)d_in[9];
  const float* kb1  = (const float*)d_in[10];
  const float* kW2  = (const float*)d_in[11];
  const float* kb2  = (const float*)d_in[12];
  const float* kW3  = (const float*)d_in[13];
  const float* kb3  = (const float*)d_in[14];
  const float* qW   = (const float*)d_in[15];
  const float* qb   = (const float*)d_in[16];
  float* out = (float*)d_out;

  // d_ws (fp8 fragments): kW1f 512KB | kW2f 1MB | kW3f 256KB | qWf 256KB = 2MB
  uint2v* kW1f = (uint2v*)d_ws;
  uint2v* kW2f = kW1f + 65536;
  uint2v* kW3f = kW2f + 131072;
  uint2v* qWf  = kW3f + 32768;

  transform_all<<<262144 / 256, 256, 0, stream>>>(kW1, kW2, kW3, qW, kW1f, kW2f, kW3f, qWf);

  policy_main<<<4096, 1024, 0, stream>>>(be, va, ph, tr, emb0, emb1, emb2, lng, lnb,
                                         kb1, kb2, kb3, qb, kW1f, kW2f, kW3f, qWf, out);
}